// Round 6
// baseline (1601.710 us; speedup 1.0000x reference)
//
#include <hip/hip_runtime.h>
#include <hip/hip_bf16.h>

// ---------------- model constants ----------------
static constexpr int SEQ   = 2048;
static constexpr int DM    = 2048;
static constexpr int NHEAD = 16;
static constexpr int NKVH  = 8;
static constexpr int HDIM  = 128;
static constexpr int FFN   = 6144;
static constexpr int NLAYER = 2;
static constexpr float EPSV = 1e-6f;
static constexpr int CHUNK = 8;   // q-heads per attention chunk
static constexpr int QKVN  = NHEAD * HDIM + 2 * NKVH * HDIM;  // 4096 fused QKV cols

typedef __attribute__((ext_vector_type(8))) short bf16x8;
typedef __attribute__((ext_vector_type(4))) float f32x4;

__device__ __forceinline__ float wave_sum(float v) {
#pragma unroll
    for (int o = 32; o > 0; o >>= 1) v += __shfl_xor(v, o);
    return v;
}
__device__ __forceinline__ float wave_max(float v) {
#pragma unroll
    for (int o = 32; o > 0; o >>= 1) v = fmaxf(v, __shfl_xor(v, o));
    return v;
}

// async global->LDS, 16B per lane
__device__ __forceinline__ void gload16(const void* g, void* l) {
    __builtin_amdgcn_global_load_lds(
        (const __attribute__((address_space(1))) void*)g,
        (__attribute__((address_space(3))) void*)l,
        16, 0, 0);
}

// ---------------- f32 -> bf16 weight convert ----------------
__global__ void cvt_bf16_k(const float* __restrict__ in, __hip_bfloat16* __restrict__ out) {
    const long b = ((long)blockIdx.x * 256 + threadIdx.x) * 8;
    const float4 a0 = *(const float4*)(in + b);
    const float4 a1 = *(const float4*)(in + b + 4);
    union { bf16x8 v; __hip_bfloat16 h[8]; } u;
    u.h[0] = __float2bfloat16(a0.x); u.h[1] = __float2bfloat16(a0.y);
    u.h[2] = __float2bfloat16(a0.z); u.h[3] = __float2bfloat16(a0.w);
    u.h[4] = __float2bfloat16(a1.x); u.h[5] = __float2bfloat16(a1.y);
    u.h[6] = __float2bfloat16(a1.z); u.h[7] = __float2bfloat16(a1.w);
    *(bf16x8*)(out + b) = u.v;
}

// ---------------- embedding gather ----------------
__global__ void embed_k(const int* __restrict__ ids, const float* __restrict__ emb,
                        float* __restrict__ h) {
    const int s = blockIdx.x;
    const long src = (long)ids[s] * DM;
    for (int t = threadIdx.x; t < DM; t += 256)
        h[(long)s * DM + t] = emb[src + t];
}

// ---------------- RMSNorm (f32 in -> bf16 out) ----------------
__global__ void rmsnorm_k(const float* __restrict__ in, const float* __restrict__ g,
                          __hip_bfloat16* __restrict__ out) {
    const int row = blockIdx.x;
    const float* r = in + (long)row * DM;
    const int tid = threadIdx.x;
    float v[8];
    float ss = 0.f;
#pragma unroll
    for (int t = 0; t < 8; ++t) { v[t] = r[tid + t * 256]; ss += v[t] * v[t]; }
    ss = wave_sum(ss);
    __shared__ float sp[4];
    if ((tid & 63) == 0) sp[tid >> 6] = ss;
    __syncthreads();
    ss = sp[0] + sp[1] + sp[2] + sp[3];
    const float inv = rsqrtf(ss * (1.f / DM) + EPSV);
    __hip_bfloat16* o_ = out + (long)row * DM;
#pragma unroll
    for (int t = 0; t < 8; ++t) {
        const int j = tid + t * 256;
        o_[j] = __float2bfloat16(v[t] * inv * g[j]);
    }
}

// ---------------- per-head RMSNorm + RoPE (one wave per (s,head)) ----------------
__global__ void qknorm_rope_k(const float* __restrict__ in, int inStride, int inOff,
                              const float* __restrict__ ns,
                              const float* __restrict__ cosT, const float* __restrict__ sinT,
                              __hip_bfloat16* __restrict__ out, int nheads, int rep) {
    const int idx = blockIdx.x * 4 + (threadIdx.x >> 6);
    const int lane = threadIdx.x & 63;
    const int s = idx / nheads;
    const int hh = idx - s * nheads;
    const float* r = in + (long)s * inStride + inOff + hh * HDIM;
    const float x1 = r[lane];
    const float x2 = r[lane + 64];
    float ss = wave_sum(x1 * x1 + x2 * x2);
    const float inv = rsqrtf(ss * (1.f / HDIM) + EPSV);
    const float n1 = x1 * inv * ns[lane];
    const float n2 = x2 * inv * ns[lane + 64];
    const float c1 = cosT[s * HDIM + lane],      c2 = cosT[s * HDIM + 64 + lane];
    const float s1 = sinT[s * HDIM + lane],      s2 = sinT[s * HDIM + 64 + lane];
    const __hip_bfloat16 o1 = __float2bfloat16(n1 * c1 - n2 * s1);
    const __hip_bfloat16 o2 = __float2bfloat16(n2 * c2 + n1 * s2);
    for (int g = 0; g < rep; ++g) {
        __hip_bfloat16* w = out + ((long)(hh * rep + g) * SEQ + s) * HDIM;
        w[lane] = o1;
        w[lane + 64] = o2;
    }
}

// ---------------- V transpose+convert (strided f32 src -> vt [qhead][d][s] bf16, GQA-repeated) --------
__global__ void vtrans_k(const float* __restrict__ vf, int rowStride, int colOff,
                         __hip_bfloat16* __restrict__ vt) {
    __shared__ float tile[64][65];
    const int s0 = blockIdx.x * 64, d0 = blockIdx.y * 64, kv = blockIdx.z;
    const int lane = threadIdx.x & 63, part = threadIdx.x >> 6;
    for (int r = part; r < 64; r += 4)
        tile[r][lane] = vf[(long)(s0 + r) * rowStride + colOff + kv * HDIM + d0 + lane];
    __syncthreads();
    for (int r = part; r < 64; r += 4) {
        const __hip_bfloat16 b = __float2bfloat16(tile[lane][r]);
        const long o0 = ((long)(2 * kv) * HDIM + d0 + r) * SEQ + s0 + lane;
        vt[o0] = b;
        vt[o0 + (long)HDIM * SEQ] = b;  // GQA-repeated copy
    }
}

// ---------------- causal softmax: f32 raw scores -> bf16 probs ----------------
__global__ void softmax_k(const float* __restrict__ sc, __hip_bfloat16* __restrict__ pr) {
    const int i = blockIdx.x;
    const long base = ((long)blockIdx.y * SEQ + i) * SEQ;
    const float* row = sc + base;
    __hip_bfloat16* orow = pr + base;
    const int tid = threadIdx.x;
    const int n = i + 1;
    const float scale = 0.0883883476483184405f;  // 1/sqrt(128)
    float m = -3.0e38f;
    for (int j = tid; j < n; j += 256) m = fmaxf(m, row[j]);
    m = wave_max(m);
    __shared__ float sm[4], ssum[4];
    const int wid = tid >> 6, lane = tid & 63;
    if (lane == 0) sm[wid] = m;
    __syncthreads();
    m = fmaxf(fmaxf(sm[0], sm[1]), fmaxf(sm[2], sm[3])) * scale;
    float s = 0.f;
    for (int j = tid; j < n; j += 256) s += __expf(row[j] * scale - m);
    s = wave_sum(s);
    if (lane == 0) ssum[wid] = s;
    __syncthreads();
    s = ssum[0] + ssum[1] + ssum[2] + ssum[3];
    const float inv = 1.f / s;
    for (int j = tid; j < SEQ; j += 256) {
        const float p = (j < n) ? __expf(row[j] * scale - m) * inv : 0.f;
        orow[j] = __float2bfloat16(p);
    }
}

// ---------------- silu(g)*u elementwise, in place on g ----------------
__global__ void silu_mul_k(__hip_bfloat16* __restrict__ g, const __hip_bfloat16* __restrict__ u) {
    const long i = ((long)blockIdx.x * 256 + threadIdx.x) * 8;
    union { bf16x8 v; __hip_bfloat16 h[8]; } a, b, o;
    a.v = *(const bf16x8*)(g + i);
    b.v = *(const bf16x8*)(u + i);
#pragma unroll
    for (int j = 0; j < 8; ++j) {
        const float xx = __bfloat162float(a.h[j]);
        const float yy = __bfloat162float(b.h[j]);
        const float sv = xx / (1.f + __expf(-xx));
        o.h[j] = __float2bfloat16(sv * yy);
    }
    *(bf16x8*)(g + i) = o.v;
}

// ---------------- split-K reduce: out = Σ2 partials (f32) ----------------
__global__ void red2_k(const float* __restrict__ p, float* __restrict__ out, long n) {
    const long i = ((long)blockIdx.x * 256 + threadIdx.x) * 4;
    float4 a = *(const float4*)(p + i);
    const float4 b = *(const float4*)(p + n + i);
    a.x += b.x; a.y += b.y; a.z += b.z; a.w += b.w;
    *(float4*)(out + i) = a;
}

// ---------------- split-K reduce: h += Σ4 partials (f32, residual in place) ----------------
__global__ void red4res_k(const float* __restrict__ p, long n, float* __restrict__ h) {
    const long i = ((long)blockIdx.x * 256 + threadIdx.x) * 4;
    float4 s = *(const float4*)(h + i);
#pragma unroll
    for (int z = 0; z < 4; ++z) {
        const float4 b = *(const float4*)(p + (long)z * n + i);
        s.x += b.x; s.y += b.y; s.z += b.z; s.w += b.w;
    }
    *(float4*)(h + i) = s;
}

// ============== 256x256 8-wave 4-phase/K-tile GEMM (m201-faithful: T2+T3+T4+T5) ==============
// C[M,N] = A[M,K(range)] * B[N,K(range)]^T.  A,B bf16 row-major (ldA/ldB).
// 512 thr = 8 waves, 2(M)x4(N), per-wave 128x64. BK=64. LDS: 2 dbuf x (A:2half + B:2half) x 16KB = 128KB.
// Per phase: stage 1 half-tile of tile t+1 (2 gload_lds) -> [p0: counted vmcnt(2)] -> barrier ->
//            ds_read A-quadrant (4xb128; +8 B at p0) -> setprio(1) 16 MFMA setprio(0) -> barrier.
// st-swizzle: 16B slot s of row r stored at s^(r&7)  (read side applies same XOR).
// z-axis: B += z*bZStride, C-index += z*cZStride, k0 += z*kZStride (split-K or dual-weight merge).
// OUT: 0 = f32 store, 1 = bf16 store.
template <int OUT>
__global__ __launch_bounds__(512, 2)
void g8p(const __hip_bfloat16* __restrict__ A, const __hip_bfloat16* __restrict__ B,
         void* __restrict__ Cv, int kLen, int ldA, int ldB, int ldC,
         long bZStride, long cZStride, int kZStride) {
    __shared__ __align__(16) char sA[2][2][16384];   // [buf][half][128 rows x 64 bf16]
    __shared__ __align__(16) char sB[2][2][16384];

    const int tid = threadIdx.x;
    const int lane = tid & 63;
    const int wid = tid >> 6;
    const int wr = wid >> 2;          // 0..1  (M half)
    const int wc = wid & 3;           // 0..3  (N quarter)
    const int l15 = lane & 15;
    const int l4 = lane >> 4;         // 0..3

    const int row0 = blockIdx.y * 256;
    const int col0 = blockIdx.x * 256;
    const int z = blockIdx.z;
    B += (long)z * bZStride;
    const long cOff = (long)z * cZStride;
    const int k0z = z * kZStride;
    const int nk = kLen / 64;

    f32x4 acc[8][4];
#pragma unroll
    for (int m = 0; m < 8; ++m)
#pragma unroll
        for (int n = 0; n < 4; ++n)
            acc[m][n] = (f32x4){0.f, 0.f, 0.f, 0.f};

    // stage one half-tile (kind 0=A0,1=A1,2=B0,3=B1) of K-tile kt into buf
    auto stage = [&](int buf, int kind, int kt) {
        const int k0 = k0z + kt * 64;
        const __hip_bfloat16* base;
        int ld_;
        char* dst;
        if (kind < 2) { base = A + (long)(row0 + kind * 128) * ldA; ld_ = ldA; dst = sA[buf][kind]; }
        else          { base = B + (long)(col0 + (kind - 2) * 128) * ldB; ld_ = ldB; dst = sB[buf][kind - 2]; }
#pragma unroll
        for (int i = 0; i < 2; ++i) {
            const int c = i * 512 + tid;          // 16B chunk 0..1023: row c>>3, dest slot c&7
            const int r = c >> 3;
            const int s = c & 7;
            gload16(base + (long)r * ld_ + k0 + ((s ^ (r & 7)) * 8), dst + c * 16);
        }
    };

    // swizzled LDS reads (logical 16B slot q of row r lives at slot q^(r&7))
    auto readA = [&](int buf, int p, int mm, int ks) -> bf16x8 {
        const int r = p * 32 + mm * 16 + l15;                 // local row in A-half wr
        const int q = ks * 4 + l4;
        return *(const bf16x8*)(sA[buf][wr] + r * 128 + ((q ^ (r & 7)) << 4));
    };
    auto readB = [&](int buf, int nn, int ks) -> bf16x8 {
        const int r = (wc & 1) * 64 + nn * 16 + l15;          // local row in B-half wc>>1
        const int q = ks * 4 + l4;
        return *(const bf16x8*)(sB[buf][wc >> 1] + r * 128 + ((q ^ (r & 7)) << 4));
    };

    // prologue: fully stage tile 0 into buf 0
    stage(0, 0, 0); stage(0, 1, 0); stage(0, 2, 0); stage(0, 3, 0);

    bf16x8 bfrag[4][2];
    for (int t = 0; t < nk; ++t) {
        const int cur = t & 1, nxt = cur ^ 1;
        const bool pre = (t + 1 < nk);
#pragma unroll
        for (int p = 0; p < 4; ++p) {
            if (pre) stage(nxt, p, t + 1);        // 1 half-tile of next K-tile, stays in flight
            if (p == 0) {
                if (pre) asm volatile("s_waitcnt vmcnt(2)" ::: "memory");  // tile t landed; A0(t+1) flying
                else     asm volatile("s_waitcnt vmcnt(0)" ::: "memory");
            }
            __builtin_amdgcn_s_barrier();
            asm volatile("" ::: "memory");
            if (p == 0) {
#pragma unroll
                for (int n = 0; n < 4; ++n) {
                    bfrag[n][0] = readB(cur, n, 0);
                    bfrag[n][1] = readB(cur, n, 1);
                }
            }
            bf16x8 a[2][2];
#pragma unroll
            for (int mm = 0; mm < 2; ++mm) {
                a[mm][0] = readA(cur, p, mm, 0);
                a[mm][1] = readA(cur, p, mm, 1);
            }
            __builtin_amdgcn_s_setprio(1);
#pragma unroll
            for (int ks = 0; ks < 2; ++ks)
#pragma unroll
                for (int mm = 0; mm < 2; ++mm)
#pragma unroll
                    for (int n = 0; n < 4; ++n)
                        acc[p * 2 + mm][n] = __builtin_amdgcn_mfma_f32_16x16x32_bf16(
                            a[mm][ks], bfrag[n][ks], acc[p * 2 + mm][n], 0, 0, 0);
            __builtin_amdgcn_s_setprio(0);
            asm volatile("" ::: "memory");
            __builtin_amdgcn_s_barrier();
        }
    }

    // epilogue: C/D layout col = lane&15, row = (lane>>4)*4 + reg (m89-verified)
#pragma unroll
    for (int m = 0; m < 8; ++m) {
#pragma unroll
        for (int n = 0; n < 4; ++n) {
            const int rb = row0 + wr * 128 + m * 16 + l4 * 4;
            const int cc = col0 + wc * 64 + n * 16 + l15;
#pragma unroll
            for (int j = 0; j < 4; ++j) {
                const long idx = cOff + (long)(rb + j) * ldC + cc;
                if constexpr (OUT == 0) ((float*)Cv)[idx] = acc[m][n][j];
                else                    ((__hip_bfloat16*)Cv)[idx] = __float2bfloat16(acc[m][n][j]);
            }
        }
    }
}

// ============== 4-wave double-buffered GEMM (attention scores / PV, unchanged) ==============
template <int BM, int BN, int OUT, int KMODE>
__global__ __launch_bounds__(256)
void gemm_db(const __hip_bfloat16* __restrict__ A, const __hip_bfloat16* __restrict__ B,
             void* __restrict__ Cv, const void* __restrict__ Resv,
             int K, int ldC, long strideA, long strideB, long strideC) {
    constexpr int BK = 64;
    constexpr int WM = BM / 2, WN = BN / 2;
    constexpr int FM = WM / 16, FN = WN / 16;
    constexpr int CA = (BM * BK) / (256 * 8);
    constexpr int CB = (BN * BK) / (256 * 8);
    static_assert(CA >= 1 && CB >= 1, "tile too small");

    __shared__ __align__(16) __hip_bfloat16 sA[2][BM * BK];
    __shared__ __align__(16) __hip_bfloat16 sB[2][BN * BK];

    const int tid = threadIdx.x;
    const int lane = tid & 63;
    const int wid = tid >> 6;
    const int wr = wid >> 1;
    const int wc = wid & 1;

    const int row0 = blockIdx.y * BM;
    const int col0 = blockIdx.x * BN;
    if (KMODE == 1 && row0 + BM - 1 < col0) return;

    const int bz = blockIdx.z;
    A += (long)bz * strideA;
    B += (long)bz * strideB;
    const long cOff = (long)bz * strideC;

    int nk = K / BK;
    if (KMODE == 2) { const int ke = row0 + BM; if (ke < K) nk = ke / BK; }

    f32x4 acc[FM][FN];
#pragma unroll
    for (int m = 0; m < FM; ++m)
#pragma unroll
        for (int n = 0; n < FN; ++n)
            acc[m][n] = (f32x4){0.f, 0.f, 0.f, 0.f};

    auto stage = [&](int buf, int kt) {
        const int k0 = kt * BK;
#pragma unroll
        for (int i = 0; i < CA; ++i) {
            const int c = i * 256 + tid;
            gload16(A + (long)(row0 + (c >> 3)) * K + (k0 + (c & 7) * 8),
                    (char*)&sA[buf][0] + c * 16);
        }
#pragma unroll
        for (int i = 0; i < CB; ++i) {
            const int c = i * 256 + tid;
            gload16(B + (long)(col0 + (c >> 3)) * K + (k0 + (c & 7) * 8),
                    (char*)&sB[buf][0] + c * 16);
        }
    };

    stage(0, 0);
    __syncthreads();

    int cur = 0;
    for (int kt = 0; kt < nk; ++kt) {
        if (kt + 1 < nk) stage(cur ^ 1, kt + 1);

        bf16x8 af[FM][2], bfr[FN][2];
#pragma unroll
        for (int ks = 0; ks < 2; ++ks) {
#pragma unroll
            for (int m = 0; m < FM; ++m)
                af[m][ks] = *(const bf16x8*)&sA[cur][(wr * WM + m * 16 + (lane & 15)) * BK + ks * 32 + (lane >> 4) * 8];
#pragma unroll
            for (int n = 0; n < FN; ++n)
                bfr[n][ks] = *(const bf16x8*)&sB[cur][(wc * WN + n * 16 + (lane & 15)) * BK + ks * 32 + (lane >> 4) * 8];
        }
#pragma unroll
        for (int ks = 0; ks < 2; ++ks)
#pragma unroll
            for (int m = 0; m < FM; ++m)
#pragma unroll
                for (int n = 0; n < FN; ++n)
                    acc[m][n] = __builtin_amdgcn_mfma_f32_16x16x32_bf16(af[m][ks], bfr[n][ks], acc[m][n], 0, 0, 0);

        __syncthreads();
        cur ^= 1;
    }

#pragma unroll
    for (int m = 0; m < FM; ++m) {
#pragma unroll
        for (int n = 0; n < FN; ++n) {
            const int rb = row0 + wr * WM + m * 16 + (lane >> 4) * 4;
            const int cc = col0 + wc * WN + n * 16 + (lane & 15);
#pragma unroll
            for (int j = 0; j < 4; ++j) {
                const long idx = cOff + (long)(rb + j) * ldC + cc;
                const float v = acc[m][n][j];
                if constexpr (OUT == 0) {
                    ((float*)Cv)[idx] = v;
                } else if constexpr (OUT == 1) {
                    ((__hip_bfloat16*)Cv)[idx] = __float2bfloat16(v);
                } else if constexpr (OUT == 2) {
                    ((float*)Cv)[idx] = v + ((const float*)Resv)[idx];
                } else {
                    const float g = __bfloat162float(((const __hip_bfloat16*)Resv)[idx]);
                    const float sg = g / (1.f + __expf(-g));
                    ((__hip_bfloat16*)Cv)[idx] = __float2bfloat16(sg * v);
                }
            }
        }
    }
}

// ---------------- host orchestration ----------------
extern "C" void kernel_launch(void* const* d_in, const int* in_sizes, int n_in,
                              void* d_out, int out_size, void* d_ws, size_t ws_size,
                              hipStream_t stream) {
    const int*   ids  = (const int*)d_in[0];
    const float* cosT = (const float*)d_in[2];
    const float* sinT = (const float*)d_in[3];
    const float* emb  = (const float*)d_in[4];
    const float* q_w  = (const float*)d_in[5];
    const float* k_w  = (const float*)d_in[6];
    const float* v_w  = (const float*)d_in[7];
    const float* o_w  = (const float*)d_in[8];
    const float* qn   = (const float*)d_in[9];
    const float* kn   = (const float*)d_in[10];
    const float* ln1  = (const float*)d_in[11];
    const float* ln2  = (const float*)d_in[12];
    const float* gw   = (const float*)d_in[13];
    const float* uw   = (const float*)d_in[14];
    const float* dw   = (const float*)d_in[15];

    char* W = (char*)d_ws;
    size_t off = 0;
    auto take = [&](size_t nb) { char* p = W + off; off += (nb + 255) & ~(size_t)255; return p; };

    // persistent bf16 weights (converted once per launch)
    __hip_bfloat16* wqkv = (__hip_bfloat16*) take((size_t)NLAYER * QKVN * DM * 2);       // [L][4096][2048]
    __hip_bfloat16* wo   = (__hip_bfloat16*) take((size_t)NLAYER * DM * (NHEAD * HDIM) * 2);
    __hip_bfloat16* wgu  = (__hip_bfloat16*) take((size_t)NLAYER * 2 * FFN * DM * 2);    // [L][gate|up][6144][2048]
    __hip_bfloat16* wd   = (__hip_bfloat16*) take((size_t)NLAYER * DM * FFN * 2);
    // activations
    float*          h      = (float*)          take((size_t)SEQ * DM * 4);
    __hip_bfloat16* x      = (__hip_bfloat16*) take((size_t)SEQ * DM * 2);
    float*          qkvf   = (float*)          take((size_t)SEQ * QKVN * 4);
    float*          part   = (float*)          take((size_t)4 * SEQ * DM * 4);           // split-K partials (67MB)
    __hip_bfloat16* qb     = (__hip_bfloat16*) take((size_t)NHEAD * SEQ * HDIM * 2);
    __hip_bfloat16* kbr    = (__hip_bfloat16*) take((size_t)NHEAD * SEQ * HDIM * 2);
    __hip_bfloat16* vtr    = (__hip_bfloat16*) take((size_t)NHEAD * HDIM * SEQ * 2);
    __hip_bfloat16* ctx    = (__hip_bfloat16*) take((size_t)SEQ * NHEAD * HDIM * 2);
    float*          scores = (float*)          take((size_t)CHUNK * SEQ * SEQ * 4);
    __hip_bfloat16* probs  = (__hip_bfloat16*) take((size_t)CHUNK * SEQ * SEQ * 2);
    __hip_bfloat16* go2    = (__hip_bfloat16*) take((size_t)2 * SEQ * FFN * 2);          // [gate|up] outputs
    if (off > ws_size) return;

    auto cvt = [&](const float* src, __hip_bfloat16* dst, long n) {
        cvt_bf16_k<<<(int)(n / 2048), 256, 0, stream>>>(src, dst);
    };

    // ---- convert all weights up front ----
    for (int l = 0; l < NLAYER; ++l) {
        __hip_bfloat16* base = wqkv + (size_t)l * QKVN * DM;
        cvt(q_w + (size_t)l * (NHEAD * HDIM) * DM, base,                               (long)(NHEAD * HDIM) * DM);
        cvt(k_w + (size_t)l * (NKVH * HDIM) * DM,  base + (size_t)(NHEAD * HDIM) * DM, (long)(NKVH * HDIM) * DM);
        cvt(v_w + (size_t)l * (NKVH * HDIM) * DM,  base + (size_t)(NHEAD * HDIM + NKVH * HDIM) * DM, (long)(NKVH * HDIM) * DM);
        cvt(gw + (size_t)l * FFN * DM, wgu + (size_t)(2 * l)     * FFN * DM, (long)FFN * DM);
        cvt(uw + (size_t)l * FFN * DM, wgu + (size_t)(2 * l + 1) * FFN * DM, (long)FFN * DM);
    }
    cvt(o_w, wo, (long)NLAYER * DM * (NHEAD * HDIM));
    cvt(dw,  wd, (long)NLAYER * DM * FFN);

    embed_k<<<SEQ, 256, 0, stream>>>(ids, emb, h);

    for (int l = 0; l < NLAYER; ++l) {
        rmsnorm_k<<<SEQ, 256, 0, stream>>>(h, ln1 + l * DM, x);

        // QKV: split-K x2 (grid 16x8x2 = 256 blocks), f32 partials -> reduce
        g8p<0><<<dim3(QKVN / 256, SEQ / 256, 2), 512, 0, stream>>>(
            x, wqkv + (size_t)l * QKVN * DM, part, DM / 2, DM, DM, QKVN,
            0L, (long)SEQ * QKVN, DM / 2);
        red2_k<<<(int)(((long)SEQ * QKVN) / 1024), 256, 0, stream>>>(part, qkvf, (long)SEQ * QKVN);

        qknorm_rope_k<<<SEQ * NHEAD / 4, 256, 0, stream>>>(
            qkvf, QKVN, 0, qn + l * HDIM, cosT, sinT, qb, NHEAD, 1);
        qknorm_rope_k<<<SEQ * NKVH / 4, 256, 0, stream>>>(
            qkvf, QKVN, NHEAD * HDIM, kn + l * HDIM, cosT, sinT, kbr, NKVH, 2);
        vtrans_k<<<dim3(SEQ / 64, HDIM / 64, NKVH), 256, 0, stream>>>(
            qkvf, QKVN, NHEAD * HDIM + NKVH * HDIM, vtr);

        for (int c = 0; c < NHEAD / CHUNK; ++c) {
            gemm_db<128, 128, 0, 1><<<dim3(SEQ / 128, SEQ / 128, CHUNK), 256, 0, stream>>>(
                qb + (size_t)c * CHUNK * SEQ * HDIM,
                kbr + (size_t)c * CHUNK * SEQ * HDIM,
                scores, nullptr,
                HDIM, SEQ, (long)SEQ * HDIM, (long)SEQ * HDIM, (long)SEQ * SEQ);
            softmax_k<<<dim3(SEQ, CHUNK), 256, 0, stream>>>(scores, probs);
            gemm_db<128, 128, 1, 2><<<dim3(HDIM / 128, SEQ / 128, CHUNK), 256, 0, stream>>>(
                probs,
                vtr + (size_t)c * CHUNK * HDIM * SEQ,
                ctx + (size_t)c * CHUNK * HDIM, nullptr,
                SEQ, NHEAD * HDIM, (long)SEQ * SEQ, (long)HDIM * SEQ, (long)HDIM);
        }

        // O: split-K x4 (grid 8x8x4 = 256 blocks), partials -> h += reduce
        g8p<0><<<dim3(DM / 256, SEQ / 256, 4), 512, 0, stream>>>(
            ctx, wo + (size_t)l * DM * (NHEAD * HDIM), part, (NHEAD * HDIM) / 4,
            NHEAD * HDIM, NHEAD * HDIM, DM, 0L, (long)SEQ * DM, (NHEAD * HDIM) / 4);
        red4res_k<<<(int)(((long)SEQ * DM) / 1024), 256, 0, stream>>>(part, (long)SEQ * DM, h);

        rmsnorm_k<<<SEQ, 256, 0, stream>>>(h, ln2 + l * DM, x);

        // gate+up merged: z picks weight & output (grid 24x8x2 = 384 blocks), bf16 out
        g8p<1><<<dim3(FFN / 256, SEQ / 256, 2), 512, 0, stream>>>(
            x, wgu + (size_t)(2 * l) * FFN * DM, go2, DM, DM, DM, FFN,
            (long)FFN * DM, (long)SEQ * FFN, 0);
        silu_mul_k<<<(int)(((long)SEQ * FFN) / 2048), 256, 0, stream>>>(go2, go2 + (size_t)SEQ * FFN);

        // down: split-K x4 (grid 8x8x4 = 256 blocks), partials -> h += reduce
        g8p<0><<<dim3(DM / 256, SEQ / 256, 4), 512, 0, stream>>>(
            go2, wd + (size_t)l * DM * FFN, part, FFN / 4,
            FFN, FFN, DM, 0L, (long)SEQ * DM, FFN / 4);
        red4res_k<<<(int)(((long)SEQ * DM) / 1024), 256, 0, stream>>>(part, (long)SEQ * DM, h);
    }

    hipMemcpyAsync(d_out, h, (size_t)out_size * sizeof(float), hipMemcpyDeviceToDevice, stream);
}

// Round 7
// 1332.798 us; speedup vs baseline: 1.2018x; 1.2018x over previous
//
#include <hip/hip_runtime.h>
#include <hip/hip_bf16.h>

// ---------------- model constants ----------------
static constexpr int SEQ   = 2048;
static constexpr int DM    = 2048;
static constexpr int NHEAD = 16;
static constexpr int NKVH  = 8;
static constexpr int HDIM  = 128;
static constexpr int FFN   = 6144;
static constexpr int NLAYER = 2;
static constexpr float EPSV = 1e-6f;
static constexpr int CHUNK = 8;   // q-heads per attention chunk
static constexpr int QKVN  = NHEAD * HDIM + 2 * NKVH * HDIM;  // 4096 fused QKV cols

typedef __attribute__((ext_vector_type(8))) short bf16x8;
typedef __attribute__((ext_vector_type(4))) float f32x4;

__device__ __forceinline__ float wave_sum(float v) {
#pragma unroll
    for (int o = 32; o > 0; o >>= 1) v += __shfl_xor(v, o);
    return v;
}
__device__ __forceinline__ float wave_max(float v) {
#pragma unroll
    for (int o = 32; o > 0; o >>= 1) v = fmaxf(v, __shfl_xor(v, o));
    return v;
}

// async global->LDS, 16B per lane
__device__ __forceinline__ void gload16(const void* g, void* l) {
    __builtin_amdgcn_global_load_lds(
        (const __attribute__((address_space(1))) void*)g,
        (__attribute__((address_space(3))) void*)l,
        16, 0, 0);
}

// ---------------- f32 -> bf16 weight convert ----------------
__global__ void cvt_bf16_k(const float* __restrict__ in, __hip_bfloat16* __restrict__ out) {
    const long b = ((long)blockIdx.x * 256 + threadIdx.x) * 8;
    const float4 a0 = *(const float4*)(in + b);
    const float4 a1 = *(const float4*)(in + b + 4);
    union { bf16x8 v; __hip_bfloat16 h[8]; } u;
    u.h[0] = __float2bfloat16(a0.x); u.h[1] = __float2bfloat16(a0.y);
    u.h[2] = __float2bfloat16(a0.z); u.h[3] = __float2bfloat16(a0.w);
    u.h[4] = __float2bfloat16(a1.x); u.h[5] = __float2bfloat16(a1.y);
    u.h[6] = __float2bfloat16(a1.z); u.h[7] = __float2bfloat16(a1.w);
    *(bf16x8*)(out + b) = u.v;
}

// ---------------- embedding gather ----------------
__global__ void embed_k(const int* __restrict__ ids, const float* __restrict__ emb,
                        float* __restrict__ h) {
    const int s = blockIdx.x;
    const long src = (long)ids[s] * DM;
    for (int t = threadIdx.x; t < DM; t += 256)
        h[(long)s * DM + t] = emb[src + t];
}

// ---------------- RMSNorm (f32 in -> bf16 out) ----------------
__global__ void rmsnorm_k(const float* __restrict__ in, const float* __restrict__ g,
                          __hip_bfloat16* __restrict__ out) {
    const int row = blockIdx.x;
    const float* r = in + (long)row * DM;
    const int tid = threadIdx.x;
    float v[8];
    float ss = 0.f;
#pragma unroll
    for (int t = 0; t < 8; ++t) { v[t] = r[tid + t * 256]; ss += v[t] * v[t]; }
    ss = wave_sum(ss);
    __shared__ float sp[4];
    if ((tid & 63) == 0) sp[tid >> 6] = ss;
    __syncthreads();
    ss = sp[0] + sp[1] + sp[2] + sp[3];
    const float inv = rsqrtf(ss * (1.f / DM) + EPSV);
    __hip_bfloat16* o_ = out + (long)row * DM;
#pragma unroll
    for (int t = 0; t < 8; ++t) {
        const int j = tid + t * 256;
        o_[j] = __float2bfloat16(v[t] * inv * g[j]);
    }
}

// ---------------- per-head RMSNorm + RoPE (one wave per (s,head)) ----------------
__global__ void qknorm_rope_k(const float* __restrict__ in, int inStride, int inOff,
                              const float* __restrict__ ns,
                              const float* __restrict__ cosT, const float* __restrict__ sinT,
                              __hip_bfloat16* __restrict__ out, int nheads, int rep) {
    const int idx = blockIdx.x * 4 + (threadIdx.x >> 6);
    const int lane = threadIdx.x & 63;
    const int s = idx / nheads;
    const int hh = idx - s * nheads;
    const float* r = in + (long)s * inStride + inOff + hh * HDIM;
    const float x1 = r[lane];
    const float x2 = r[lane + 64];
    float ss = wave_sum(x1 * x1 + x2 * x2);
    const float inv = rsqrtf(ss * (1.f / HDIM) + EPSV);
    const float n1 = x1 * inv * ns[lane];
    const float n2 = x2 * inv * ns[lane + 64];
    const float c1 = cosT[s * HDIM + lane],      c2 = cosT[s * HDIM + 64 + lane];
    const float s1 = sinT[s * HDIM + lane],      s2 = sinT[s * HDIM + 64 + lane];
    const __hip_bfloat16 o1 = __float2bfloat16(n1 * c1 - n2 * s1);
    const __hip_bfloat16 o2 = __float2bfloat16(n2 * c2 + n1 * s2);
    for (int g = 0; g < rep; ++g) {
        __hip_bfloat16* w = out + ((long)(hh * rep + g) * SEQ + s) * HDIM;
        w[lane] = o1;
        w[lane + 64] = o2;
    }
}

// ---------------- V transpose+convert (strided f32 src -> vt [qhead][d][s] bf16, GQA-repeated) --------
__global__ void vtrans_k(const float* __restrict__ vf, int rowStride, int colOff,
                         __hip_bfloat16* __restrict__ vt) {
    __shared__ float tile[64][65];
    const int s0 = blockIdx.x * 64, d0 = blockIdx.y * 64, kv = blockIdx.z;
    const int lane = threadIdx.x & 63, part = threadIdx.x >> 6;
    for (int r = part; r < 64; r += 4)
        tile[r][lane] = vf[(long)(s0 + r) * rowStride + colOff + kv * HDIM + d0 + lane];
    __syncthreads();
    for (int r = part; r < 64; r += 4) {
        const __hip_bfloat16 b = __float2bfloat16(tile[lane][r]);
        const long o0 = ((long)(2 * kv) * HDIM + d0 + r) * SEQ + s0 + lane;
        vt[o0] = b;
        vt[o0 + (long)HDIM * SEQ] = b;  // GQA-repeated copy
    }
}

// ---------------- causal softmax: f32 raw scores -> bf16 probs ----------------
__global__ void softmax_k(const float* __restrict__ sc, __hip_bfloat16* __restrict__ pr) {
    const int i = blockIdx.x;
    const long base = ((long)blockIdx.y * SEQ + i) * SEQ;
    const float* row = sc + base;
    __hip_bfloat16* orow = pr + base;
    const int tid = threadIdx.x;
    const int n = i + 1;
    const float scale = 0.0883883476483184405f;  // 1/sqrt(128)
    float m = -3.0e38f;
    for (int j = tid; j < n; j += 256) m = fmaxf(m, row[j]);
    m = wave_max(m);
    __shared__ float sm[4], ssum[4];
    const int wid = tid >> 6, lane = tid & 63;
    if (lane == 0) sm[wid] = m;
    __syncthreads();
    m = fmaxf(fmaxf(sm[0], sm[1]), fmaxf(sm[2], sm[3])) * scale;
    float s = 0.f;
    for (int j = tid; j < n; j += 256) s += __expf(row[j] * scale - m);
    s = wave_sum(s);
    if (lane == 0) ssum[wid] = s;
    __syncthreads();
    s = ssum[0] + ssum[1] + ssum[2] + ssum[3];
    const float inv = 1.f / s;
    for (int j = tid; j < SEQ; j += 256) {
        const float p = (j < n) ? __expf(row[j] * scale - m) * inv : 0.f;
        orow[j] = __float2bfloat16(p);
    }
}

// ---------------- silu(g)*u elementwise, in place on g ----------------
__global__ void silu_mul_k(__hip_bfloat16* __restrict__ g, const __hip_bfloat16* __restrict__ u) {
    const long i = ((long)blockIdx.x * 256 + threadIdx.x) * 8;
    union { bf16x8 v; __hip_bfloat16 h[8]; } a, b, o;
    a.v = *(const bf16x8*)(g + i);
    b.v = *(const bf16x8*)(u + i);
#pragma unroll
    for (int j = 0; j < 8; ++j) {
        const float xx = __bfloat162float(a.h[j]);
        const float yy = __bfloat162float(b.h[j]);
        const float sv = xx / (1.f + __expf(-xx));
        o.h[j] = __float2bfloat16(sv * yy);
    }
    *(bf16x8*)(g + i) = o.v;
}

// ---------------- split-K reduce: out = Σ2 partials (f32) ----------------
__global__ void red2_k(const float* __restrict__ p, float* __restrict__ out, long n) {
    const long i = ((long)blockIdx.x * 256 + threadIdx.x) * 4;
    float4 a = *(const float4*)(p + i);
    const float4 b = *(const float4*)(p + n + i);
    a.x += b.x; a.y += b.y; a.z += b.z; a.w += b.w;
    *(float4*)(out + i) = a;
}

// ---------------- split-K reduce: h += Σ4 partials (f32, residual in place) ----------------
__global__ void red4res_k(const float* __restrict__ p, long n, float* __restrict__ h) {
    const long i = ((long)blockIdx.x * 256 + threadIdx.x) * 4;
    float4 s = *(const float4*)(h + i);
#pragma unroll
    for (int z = 0; z < 4; ++z) {
        const float4 b = *(const float4*)(p + (long)z * n + i);
        s.x += b.x; s.y += b.y; s.z += b.z; s.w += b.w;
    }
    *(float4*)(h + i) = s;
}

// ============== 256x256 8-wave GEMM, m201-faithful phase schedule ==============
// C[M,N] = A[M,K(range)] * B[N,K(range)]^T.  A,B bf16 row-major (ldA/ldB).
// 512 thr = 8 waves, 2(M)x4(N), per-wave 128x64. BK=64. LDS 2dbuf x 4 halves x 16KB = 128KB.
// Phase (t,p): {ds_read A-quad p (4xb128; +8 B at p0) || stage 1 half-tile} ->
//   [p0: lgkmcnt(8)] -> [p3: vmcnt(4)] -> s_barrier -> lgkmcnt(0) ->
//   setprio(1) 16 MFMA setprio(0) -> s_barrier.
// Staging schedule: A(t+1) at p0,p1 (slots free since t-1 ended);
//                   B(t+2) at p2,p3 (B(t) slots dead after p0's B reads + barrier).
// vmcnt(4)@p3 confirms A(t+1)+B(t+1), leaves B(t+2)'s 2 halves (4 loads) in flight.
// st-swizzle: 16B slot s of row r stored at s^(r&7); read applies same XOR. (R6: 0 conflicts)
// z-axis: B += z*bZStride, C += z*cZStride, k0 += z*kZStride. OUT: 0=f32 store, 1=bf16 store.
template <int OUT>
__global__ __launch_bounds__(512, 2)
void g8p(const __hip_bfloat16* __restrict__ A, const __hip_bfloat16* __restrict__ B,
         void* __restrict__ Cv, int kLen, int ldA, int ldB, int ldC,
         long bZStride, long cZStride, int kZStride) {
    __shared__ __align__(16) char sA[2][2][16384];   // [buf][half][128 rows x 64 bf16]
    __shared__ __align__(16) char sB[2][2][16384];

    const int tid = threadIdx.x;
    const int lane = tid & 63;
    const int wid = tid >> 6;
    const int wr = wid >> 2;          // 0..1  (M half)
    const int wc = wid & 3;           // 0..3  (N quarter)
    const int l15 = lane & 15;
    const int l4 = lane >> 4;         // 0..3

    const int row0 = blockIdx.y * 256;
    const int col0 = blockIdx.x * 256;
    const int z = blockIdx.z;
    B += (long)z * bZStride;
    const long cOff = (long)z * cZStride;
    const int k0z = z * kZStride;
    const int nk = kLen / 64;         // callers guarantee nk >= 3

    f32x4 acc[8][4];
#pragma unroll
    for (int m = 0; m < 8; ++m)
#pragma unroll
        for (int n = 0; n < 4; ++n)
            acc[m][n] = (f32x4){0.f, 0.f, 0.f, 0.f};

    // stage one half-tile (kind 0,1 = A halves; 2,3 = B halves) of K-tile kt into buf kt&1
    auto stage = [&](int kind, int kt) {
        const int k0 = k0z + kt * 64;
        const __hip_bfloat16* base;
        int ld_;
        char* dst;
        if (kind < 2) { base = A + (long)(row0 + kind * 128) * ldA; ld_ = ldA; dst = sA[kt & 1][kind]; }
        else          { base = B + (long)(col0 + (kind - 2) * 128) * ldB; ld_ = ldB; dst = sB[kt & 1][kind - 2]; }
#pragma unroll
        for (int i = 0; i < 2; ++i) {
            const int c = i * 512 + tid;          // 16B chunk 0..1023: row c>>3, dest slot c&7
            const int r = c >> 3;
            const int s = c & 7;
            gload16(base + (long)r * ld_ + k0 + ((s ^ (r & 7)) * 8), dst + c * 16);
        }
    };

    // swizzled LDS reads (logical 16B slot q of row r lives at slot q^(r&7))
    auto readA = [&](int buf, int p, int mm, int ks) -> bf16x8 {
        const int r = p * 32 + mm * 16 + l15;                 // local row in A-half wr
        const int q = ks * 4 + l4;
        return *(const bf16x8*)(sA[buf][wr] + r * 128 + ((q ^ (r & 7)) << 4));
    };
    auto readB = [&](int buf, int nn, int ks) -> bf16x8 {
        const int r = (wc & 1) * 64 + nn * 16 + l15;          // local row in B-half wc>>1
        const int q = ks * 4 + l4;
        return *(const bf16x8*)(sB[buf][wc >> 1] + r * 128 + ((q ^ (r & 7)) << 4));
    };

    // ---- prologue: A(0), B(0), B(1); confirm tile 0; B(1) stays in flight ----
    stage(0, 0); stage(1, 0); stage(2, 0); stage(3, 0);
    stage(2, 1); stage(3, 1);
    asm volatile("s_waitcnt vmcnt(4)" ::: "memory");   // A(0)+B(0) landed
    __builtin_amdgcn_s_barrier();

    bf16x8 bfrag[4][2];
    for (int t = 0; t < nk; ++t) {
        const int cur = t & 1;
#pragma unroll
        for (int p = 0; p < 4; ++p) {
            // ---- ds_read this phase's fragments (buf confirmed a tile ago) ----
            bf16x8 a[2][2];
            a[0][0] = readA(cur, p, 0, 0); a[0][1] = readA(cur, p, 0, 1);
            a[1][0] = readA(cur, p, 1, 0); a[1][1] = readA(cur, p, 1, 1);
            if (p == 0) {
#pragma unroll
                for (int n = 0; n < 4; ++n) {
                    bfrag[n][0] = readB(cur, n, 0);
                    bfrag[n][1] = readB(cur, n, 1);
                }
            }
            // ---- stage one half-tile: A(t+1) at p0/p1, B(t+2) at p2/p3 ----
            if (p == 0 && t + 1 < nk) stage(0, t + 1);
            if (p == 1 && t + 1 < nk) stage(1, t + 1);
            if (p == 2 && t + 2 < nk) stage(2, t + 2);
            if (p == 3 && t + 2 < nk) stage(3, t + 2);

            if (p == 0) asm volatile("s_waitcnt lgkmcnt(8)" ::: "memory");
            __builtin_amdgcn_sched_barrier(0);
            if (p == 3) {
                if (t + 2 < nk)      asm volatile("s_waitcnt vmcnt(4)" ::: "memory");  // next tile landed
                else if (t + 1 < nk) asm volatile("s_waitcnt vmcnt(0)" ::: "memory");  // final drain
            }
            __builtin_amdgcn_s_barrier();
            asm volatile("s_waitcnt lgkmcnt(0)" ::: "memory");
            __builtin_amdgcn_sched_barrier(0);

            __builtin_amdgcn_s_setprio(1);
#pragma unroll
            for (int ks = 0; ks < 2; ++ks)
#pragma unroll
                for (int mm = 0; mm < 2; ++mm)
#pragma unroll
                    for (int n = 0; n < 4; ++n)
                        acc[p * 2 + mm][n] = __builtin_amdgcn_mfma_f32_16x16x32_bf16(
                            a[mm][ks], bfrag[n][ks], acc[p * 2 + mm][n], 0, 0, 0);
            __builtin_amdgcn_s_setprio(0);
            __builtin_amdgcn_sched_barrier(0);
            __builtin_amdgcn_s_barrier();
        }
    }

    // epilogue: C/D layout col = lane&15, row = (lane>>4)*4 + reg (m89-verified)
#pragma unroll
    for (int m = 0; m < 8; ++m) {
#pragma unroll
        for (int n = 0; n < 4; ++n) {
            const int rb = row0 + wr * 128 + m * 16 + l4 * 4;
            const int cc = col0 + wc * 64 + n * 16 + l15;
#pragma unroll
            for (int j = 0; j < 4; ++j) {
                const long idx = cOff + (long)(rb + j) * ldC + cc;
                if constexpr (OUT == 0) ((float*)Cv)[idx] = acc[m][n][j];
                else                    ((__hip_bfloat16*)Cv)[idx] = __float2bfloat16(acc[m][n][j]);
            }
        }
    }
}

// ============== 4-wave double-buffered GEMM (attention scores / PV, unchanged) ==============
template <int BM, int BN, int OUT, int KMODE>
__global__ __launch_bounds__(256)
void gemm_db(const __hip_bfloat16* __restrict__ A, const __hip_bfloat16* __restrict__ B,
             void* __restrict__ Cv, const void* __restrict__ Resv,
             int K, int ldC, long strideA, long strideB, long strideC) {
    constexpr int BK = 64;
    constexpr int WM = BM / 2, WN = BN / 2;
    constexpr int FM = WM / 16, FN = WN / 16;
    constexpr int CA = (BM * BK) / (256 * 8);
    constexpr int CB = (BN * BK) / (256 * 8);
    static_assert(CA >= 1 && CB >= 1, "tile too small");

    __shared__ __align__(16) __hip_bfloat16 sA[2][BM * BK];
    __shared__ __align__(16) __hip_bfloat16 sB[2][BN * BK];

    const int tid = threadIdx.x;
    const int lane = tid & 63;
    const int wid = tid >> 6;
    const int wr = wid >> 1;
    const int wc = wid & 1;

    const int row0 = blockIdx.y * BM;
    const int col0 = blockIdx.x * BN;
    if (KMODE == 1 && row0 + BM - 1 < col0) return;

    const int bz = blockIdx.z;
    A += (long)bz * strideA;
    B += (long)bz * strideB;
    const long cOff = (long)bz * strideC;

    int nk = K / BK;
    if (KMODE == 2) { const int ke = row0 + BM; if (ke < K) nk = ke / BK; }

    f32x4 acc[FM][FN];
#pragma unroll
    for (int m = 0; m < FM; ++m)
#pragma unroll
        for (int n = 0; n < FN; ++n)
            acc[m][n] = (f32x4){0.f, 0.f, 0.f, 0.f};

    auto stage = [&](int buf, int kt) {
        const int k0 = kt * BK;
#pragma unroll
        for (int i = 0; i < CA; ++i) {
            const int c = i * 256 + tid;
            gload16(A + (long)(row0 + (c >> 3)) * K + (k0 + (c & 7) * 8),
                    (char*)&sA[buf][0] + c * 16);
        }
#pragma unroll
        for (int i = 0; i < CB; ++i) {
            const int c = i * 256 + tid;
            gload16(B + (long)(col0 + (c >> 3)) * K + (k0 + (c & 7) * 8),
                    (char*)&sB[buf][0] + c * 16);
        }
    };

    stage(0, 0);
    __syncthreads();

    int cur = 0;
    for (int kt = 0; kt < nk; ++kt) {
        if (kt + 1 < nk) stage(cur ^ 1, kt + 1);

        bf16x8 af[FM][2], bfr[FN][2];
#pragma unroll
        for (int ks = 0; ks < 2; ++ks) {
#pragma unroll
            for (int m = 0; m < FM; ++m)
                af[m][ks] = *(const bf16x8*)&sA[cur][(wr * WM + m * 16 + (lane & 15)) * BK + ks * 32 + (lane >> 4) * 8];
#pragma unroll
            for (int n = 0; n < FN; ++n)
                bfr[n][ks] = *(const bf16x8*)&sB[cur][(wc * WN + n * 16 + (lane & 15)) * BK + ks * 32 + (lane >> 4) * 8];
        }
#pragma unroll
        for (int ks = 0; ks < 2; ++ks)
#pragma unroll
            for (int m = 0; m < FM; ++m)
#pragma unroll
                for (int n = 0; n < FN; ++n)
                    acc[m][n] = __builtin_amdgcn_mfma_f32_16x16x32_bf16(af[m][ks], bfr[n][ks], acc[m][n], 0, 0, 0);

        __syncthreads();
        cur ^= 1;
    }

#pragma unroll
    for (int m = 0; m < FM; ++m) {
#pragma unroll
        for (int n = 0; n < FN; ++n) {
            const int rb = row0 + wr * WM + m * 16 + (lane >> 4) * 4;
            const int cc = col0 + wc * WN + n * 16 + (lane & 15);
#pragma unroll
            for (int j = 0; j < 4; ++j) {
                const long idx = cOff + (long)(rb + j) * ldC + cc;
                const float v = acc[m][n][j];
                if constexpr (OUT == 0) {
                    ((float*)Cv)[idx] = v;
                } else if constexpr (OUT == 1) {
                    ((__hip_bfloat16*)Cv)[idx] = __float2bfloat16(v);
                } else if constexpr (OUT == 2) {
                    ((float*)Cv)[idx] = v + ((const float*)Resv)[idx];
                } else {
                    const float g = __bfloat162float(((const __hip_bfloat16*)Resv)[idx]);
                    const float sg = g / (1.f + __expf(-g));
                    ((__hip_bfloat16*)Cv)[idx] = __float2bfloat16(sg * v);
                }
            }
        }
    }
}

// ---------------- host orchestration ----------------
extern "C" void kernel_launch(void* const* d_in, const int* in_sizes, int n_in,
                              void* d_out, int out_size, void* d_ws, size_t ws_size,
                              hipStream_t stream) {
    const int*   ids  = (const int*)d_in[0];
    const float* cosT = (const float*)d_in[2];
    const float* sinT = (const float*)d_in[3];
    const float* emb  = (const float*)d_in[4];
    const float* q_w  = (const float*)d_in[5];
    const float* k_w  = (const float*)d_in[6];
    const float* v_w  = (const float*)d_in[7];
    const float* o_w  = (const float*)d_in[8];
    const float* qn   = (const float*)d_in[9];
    const float* kn   = (const float*)d_in[10];
    const float* ln1  = (const float*)d_in[11];
    const float* ln2  = (const float*)d_in[12];
    const float* gw   = (const float*)d_in[13];
    const float* uw   = (const float*)d_in[14];
    const float* dw   = (const float*)d_in[15];

    char* W = (char*)d_ws;
    size_t off = 0;
    auto take = [&](size_t nb) { char* p = W + off; off += (nb + 255) & ~(size_t)255; return p; };

    // persistent bf16 weights (converted once per launch)
    __hip_bfloat16* wqkv = (__hip_bfloat16*) take((size_t)NLAYER * QKVN * DM * 2);       // [L][4096][2048]
    __hip_bfloat16* wo   = (__hip_bfloat16*) take((size_t)NLAYER * DM * (NHEAD * HDIM) * 2);
    __hip_bfloat16* wgu  = (__hip_bfloat16*) take((size_t)NLAYER * 2 * FFN * DM * 2);    // [L][gate|up][6144][2048]
    __hip_bfloat16* wd   = (__hip_bfloat16*) take((size_t)NLAYER * DM * FFN * 2);
    // activations
    float*          h      = (float*)          take((size_t)SEQ * DM * 4);
    __hip_bfloat16* x      = (__hip_bfloat16*) take((size_t)SEQ * DM * 2);
    float*          qkvf   = (float*)          take((size_t)SEQ * QKVN * 4);
    float*          part   = (float*)          take((size_t)4 * SEQ * DM * 4);           // split-K partials
    __hip_bfloat16* qb     = (__hip_bfloat16*) take((size_t)NHEAD * SEQ * HDIM * 2);
    __hip_bfloat16* kbr    = (__hip_bfloat16*) take((size_t)NHEAD * SEQ * HDIM * 2);
    __hip_bfloat16* vtr    = (__hip_bfloat16*) take((size_t)NHEAD * HDIM * SEQ * 2);
    __hip_bfloat16* ctx    = (__hip_bfloat16*) take((size_t)SEQ * NHEAD * HDIM * 2);
    float*          scores = (float*)          take((size_t)CHUNK * SEQ * SEQ * 4);
    __hip_bfloat16* probs  = (__hip_bfloat16*) take((size_t)CHUNK * SEQ * SEQ * 2);
    __hip_bfloat16* go2    = (__hip_bfloat16*) take((size_t)2 * SEQ * FFN * 2);          // [gate|up] outputs
    if (off > ws_size) return;

    auto cvt = [&](const float* src, __hip_bfloat16* dst, long n) {
        cvt_bf16_k<<<(int)(n / 2048), 256, 0, stream>>>(src, dst);
    };

    // ---- convert all weights up front ----
    for (int l = 0; l < NLAYER; ++l) {
        __hip_bfloat16* base = wqkv + (size_t)l * QKVN * DM;
        cvt(q_w + (size_t)l * (NHEAD * HDIM) * DM, base,                               (long)(NHEAD * HDIM) * DM);
        cvt(k_w + (size_t)l * (NKVH * HDIM) * DM,  base + (size_t)(NHEAD * HDIM) * DM, (long)(NKVH * HDIM) * DM);
        cvt(v_w + (size_t)l * (NKVH * HDIM) * DM,  base + (size_t)(NHEAD * HDIM + NKVH * HDIM) * DM, (long)(NKVH * HDIM) * DM);
        cvt(gw + (size_t)l * FFN * DM, wgu + (size_t)(2 * l)     * FFN * DM, (long)FFN * DM);
        cvt(uw + (size_t)l * FFN * DM, wgu + (size_t)(2 * l + 1) * FFN * DM, (long)FFN * DM);
    }
    cvt(o_w, wo, (long)NLAYER * DM * (NHEAD * HDIM));
    cvt(dw,  wd, (long)NLAYER * DM * FFN);

    embed_k<<<SEQ, 256, 0, stream>>>(ids, emb, h);

    for (int l = 0; l < NLAYER; ++l) {
        rmsnorm_k<<<SEQ, 256, 0, stream>>>(h, ln1 + l * DM, x);

        // QKV: split-K x2 (grid 16x8x2 = 256 blocks), f32 partials -> reduce
        g8p<0><<<dim3(QKVN / 256, SEQ / 256, 2), 512, 0, stream>>>(
            x, wqkv + (size_t)l * QKVN * DM, part, DM / 2, DM, DM, QKVN,
            0L, (long)SEQ * QKVN, DM / 2);
        red2_k<<<(int)(((long)SEQ * QKVN) / 1024), 256, 0, stream>>>(part, qkvf, (long)SEQ * QKVN);

        qknorm_rope_k<<<SEQ * NHEAD / 4, 256, 0, stream>>>(
            qkvf, QKVN, 0, qn + l * HDIM, cosT, sinT, qb, NHEAD, 1);
        qknorm_rope_k<<<SEQ * NKVH / 4, 256, 0, stream>>>(
            qkvf, QKVN, NHEAD * HDIM, kn + l * HDIM, cosT, sinT, kbr, NKVH, 2);
        vtrans_k<<<dim3(SEQ / 64, HDIM / 64, NKVH), 256, 0, stream>>>(
            qkvf, QKVN, NHEAD * HDIM + NKVH * HDIM, vtr);

        for (int c = 0; c < NHEAD / CHUNK; ++c) {
            gemm_db<128, 128, 0, 1><<<dim3(SEQ / 128, SEQ / 128, CHUNK), 256, 0, stream>>>(
                qb + (size_t)c * CHUNK * SEQ * HDIM,
                kbr + (size_t)c * CHUNK * SEQ * HDIM,
                scores, nullptr,
                HDIM, SEQ, (long)SEQ * HDIM, (long)SEQ * HDIM, (long)SEQ * SEQ);
            softmax_k<<<dim3(SEQ, CHUNK), 256, 0, stream>>>(scores, probs);
            gemm_db<128, 128, 1, 2><<<dim3(HDIM / 128, SEQ / 128, CHUNK), 256, 0, stream>>>(
                probs,
                vtr + (size_t)c * CHUNK * HDIM * SEQ,
                ctx + (size_t)c * CHUNK * HDIM, nullptr,
                SEQ, NHEAD * HDIM, (long)SEQ * SEQ, (long)HDIM * SEQ, (long)HDIM);
        }

        // O: split-K x4 (grid 8x8x4 = 256 blocks), partials -> h += reduce
        g8p<0><<<dim3(DM / 256, SEQ / 256, 4), 512, 0, stream>>>(
            ctx, wo + (size_t)l * DM * (NHEAD * HDIM), part, (NHEAD * HDIM) / 4,
            NHEAD * HDIM, NHEAD * HDIM, DM, 0L, (long)SEQ * DM, (NHEAD * HDIM) / 4);
        red4res_k<<<(int)(((long)SEQ * DM) / 1024), 256, 0, stream>>>(part, (long)SEQ * DM, h);

        rmsnorm_k<<<SEQ, 256, 0, stream>>>(h, ln2 + l * DM, x);

        // gate+up merged: z picks weight & output (grid 24x8x2 = 384 blocks), bf16 out
        g8p<1><<<dim3(FFN / 256, SEQ / 256, 2), 512, 0, stream>>>(
            x, wgu + (size_t)(2 * l) * FFN * DM, go2, DM, DM, DM, FFN,
            (long)FFN * DM, (long)SEQ * FFN, 0);
        silu_mul_k<<<(int)(((long)SEQ * FFN) / 2048), 256, 0, stream>>>(go2, go2 + (size_t)SEQ * FFN);

        // down: split-K x4 (grid 8x8x4 = 256 blocks), partials -> h += reduce
        g8p<0><<<dim3(DM / 256, SEQ / 256, 4), 512, 0, stream>>>(
            go2, wd + (size_t)l * DM * FFN, part, FFN / 4,
            FFN, FFN, DM, 0L, (long)SEQ * DM, FFN / 4);
        red4res_k<<<(int)(((long)SEQ * DM) / 1024), 256, 0, stream>>>(part, (long)SEQ * DM, h);
    }

    hipMemcpyAsync(d_out, h, (size_t)out_size * sizeof(float), hipMemcpyDeviceToDevice, stream);
}